// Round 5
// baseline (2160.892 us; speedup 1.0000x reference)
//
#include <hip/hip_runtime.h>
#include <hip/hip_fp16.h>

#define Sn 128
#define Bn 64
#define Hn 512
#define Vn 100
#define TSn 31   // T-1 steps

typedef unsigned int   u32;
typedef unsigned short u16;
typedef _Float16 f16x2 __attribute__((ext_vector_type(2)));

// ---- ws byte offsets (fp16 weights + LLC exchange buffers; ~5.33 MB total) ----
#define OFF_WEMB  0ull          // fp16 [V][H]        102,400
#define OFF_WCOMB 102400ull     // fp16 [H][2H]     1,048,576
#define OFF_WIH   1150976ull    // fp16 [3H][H]     1,572,864
#define OFF_WHH   2723840ull    // fp16 [3H][H]     1,572,864
#define OFF_WOUT  4296704ull    // fp16 [V][H]        102,400
#define OFF_PCTX  4399104ull    // u32  [32][8][2][256]  524,288
#define OFF_ML    4923392ull    // f32  [32][8][2][2]      4,096
#define OFF_XEX   4927488ull    // u32  [32][8][2][32]    65,536
#define OFF_HEX   4993024ull    // f32  [32][8][2][64]   131,072
#define OFF_PLOG  5124096ull    // f32  [32][8][2][100]  204,800
#define OFF_CNT   5328896ull    // u32  [3][32]              384

__device__ __forceinline__ u16 f2h(float f){ _Float16 h=(_Float16)f; return __builtin_bit_cast(u16,h); }
__device__ __forceinline__ f16x2 uh2(u32 u){ return __builtin_bit_cast(f16x2,u); }
__device__ __forceinline__ float2 h2f(u32 u){ f16x2 h=uh2(u); return make_float2((float)h.x,(float)h.y); }
__device__ __forceinline__ u32 pack2h(float a, float b){ return (u32)f2h(a) | ((u32)f2h(b) << 16); }

#if __has_builtin(__builtin_amdgcn_fdot2)
__device__ __forceinline__ float dot2acc(u32 a, u32 b, float acc){
    return __builtin_amdgcn_fdot2(uh2(a), uh2(b), acc, false);
}
#else
__device__ __forceinline__ float dot2acc(u32 a, u32 b, float acc){
    float2 x=h2f(a), y=h2f(b); return acc + x.x*y.x + x.y*y.y;
}
#endif

__device__ __forceinline__ float dot8h(uint4 w, uint4 v, float acc){
    acc = dot2acc(w.x, v.x, acc); acc = dot2acc(w.y, v.y, acc);
    acc = dot2acc(w.z, v.z, acc); acc = dot2acc(w.w, v.w, acc);
    return acc;
}

__device__ __forceinline__ float fast_tanh(float x){
    float e = __expf(2.0f*x);
    return 1.0f - 2.0f/(e + 1.0f);
}
__device__ __forceinline__ float fast_sigmoid(float x){ return 1.0f/(1.0f + __expf(-x)); }

__device__ __forceinline__ float wave_sum(float v){
#pragma unroll
    for (int o = 32; o; o >>= 1) v += __shfl_xor(v, o);
    return v;
}
__device__ __forceinline__ float wave_max(float v){
#pragma unroll
    for (int o = 32; o; o >>= 1) v = fmaxf(v, __shfl_xor(v, o));
    return v;
}
// reduction within a 32-lane half-wave (xor offsets stay inside the half)
__device__ __forceinline__ float half_sum(float v){
#pragma unroll
    for (int o = 16; o; o >>= 1) v += __shfl_xor(v, o);
    return v;
}

// 8-sibling group barrier pieces (LLC atomics, monotonic counter; proven in round 4)
__device__ __forceinline__ void sib_arrive(u32* cnt){
    asm volatile("s_waitcnt vmcnt(0)" ::: "memory");   // drain this wave's volatile stores
    __syncthreads();                                    // all waves drained
    if (threadIdx.x == 0)
        __hip_atomic_fetch_add(cnt, 1u, __ATOMIC_RELAXED, __HIP_MEMORY_SCOPE_AGENT);
}
__device__ __forceinline__ void sib_wait(u32* cnt, u32 target){
    if (threadIdx.x == 0) {
        u32 v;
        do { __builtin_amdgcn_s_sleep(1);
             v = __hip_atomic_load(cnt, __ATOMIC_RELAXED, __HIP_MEMORY_SCOPE_AGENT);
        } while (v < target);
    }
    __syncthreads();
}

// ---------------- pre-pass: weights fp32 -> fp16, zero barrier counters ----------------
#define CONV(S,D,N)                                              \
    for (int i = t0; i < (N)/4; i += stride) {                   \
        float4 v = ((const float4*)(S))[i];                      \
        ushort4 o;                                               \
        o.x = f2h(v.x); o.y = f2h(v.y);                          \
        o.z = f2h(v.z); o.w = f2h(v.w);                          \
        ((ushort4*)(D))[i] = o;                                  \
    }

__global__ __launch_bounds__(256) void conv_f16(
    const float* __restrict__ Wemb, const float* __restrict__ Wcomb,
    const float* __restrict__ Wih, const float* __restrict__ Whh,
    const float* __restrict__ Wout, char* __restrict__ ws)
{
    const int t0 = blockIdx.x*256 + threadIdx.x;
    const int stride = gridDim.x*256;
    if (blockIdx.x == 0 && threadIdx.x < 96) ((u32*)(ws + OFF_CNT))[threadIdx.x] = 0;
    u16* dm = (u16*)(ws + OFF_WEMB);
    u16* dc = (u16*)(ws + OFF_WCOMB);
    u16* di = (u16*)(ws + OFF_WIH);
    u16* dh = (u16*)(ws + OFF_WHH);
    u16* doo = (u16*)(ws + OFF_WOUT);
    CONV(Wemb, dm, Vn*Hn)
    CONV(Wcomb,dc, Hn*2*Hn)
    CONV(Wih,  di, 3*Hn*Hn)
    CONV(Whh,  dh, 3*Hn*Hn)
    CONV(Wout, doo, Vn*Hn)
}

// ---------------- main kernel ----------------
// 256 blocks = 32 groups (b-pair) x 8 siblings. Sibling q (= XCD bid&7) owns
// j in [64q,64q+64), s in [16q,16q+16). Weight j-slices stay L2-resident per XCD.
__global__ __launch_bounds__(1024) void bahdanau_decoder(
    const float* __restrict__ encf, const float* __restrict__ bcomb,
    const float* __restrict__ bih, const float* __restrict__ bhh,
    const float* __restrict__ bout, const float* __restrict__ wvat,
    const float* __restrict__ bvat, const int* __restrict__ tgt,
    float* __restrict__ out, char* __restrict__ ws)
{
    const u16* Wemb_h  = (const u16*)(ws + OFF_WEMB);
    const u16* Wcomb_h = (const u16*)(ws + OFF_WCOMB);
    const u16* Wih_h   = (const u16*)(ws + OFF_WIH);
    const u16* Whh_h   = (const u16*)(ws + OFF_WHH);
    const u16* Wout_h  = (const u16*)(ws + OFF_WOUT);
    volatile u32*   PCTX = (volatile u32*)(ws + OFF_PCTX);
    volatile float* ML   = (volatile float*)(ws + OFF_ML);
    volatile u32*   XEX  = (volatile u32*)(ws + OFF_XEX);
    volatile float* HEX  = (volatile float*)(ws + OFF_HEX);
    volatile float* PLOG = (volatile float*)(ws + OFF_PLOG);
    u32* CNT = (u32*)(ws + OFF_CNT);

    __shared__ __align__(16) u16   enc_lds[2][16][Hn];  // own 16 s rows x 2 b, fp16 32KB
    __shared__ __align__(16) float h_s[2][Hn];          // fp32 recurrent state (full)
    __shared__ __align__(16) u16   hh_s[2][Hn];         // fp16 h
    __shared__ __align__(16) u16   ec_s[2][2*Hn];       // [emb ; ctx] per b
    __shared__ __align__(16) u16   x_s[2][Hn];          // full x (assembled)
    __shared__ __align__(16) u16   xst[2][64];          // own x slice staging
    __shared__ __align__(16) float sc_s[2][16];         // own scores
    __shared__ __align__(16) float attnw_s[2][16];      // local exp(s-m)
    __shared__ __align__(16) float fac_s[2][8];         // e^{m_q - M}
    __shared__ __align__(16) float linv_s[2];
    __shared__ __align__(16) float2 pctx_s[2][2][256];  // ctx partial accum
    __shared__ __align__(16) u16   hn16_s[2][64];       // h_new own slice fp16
    __shared__ __align__(16) float plog_s[2][112];

    const int tid  = threadIdx.x;
    const int lane = tid & 63;
    const int wid  = tid >> 6;          // 0..15
    const int half = lane >> 5;         // b within pair for split phases
    const int l5   = lane & 31;
    const int bid  = blockIdx.x;
    const int g    = bid >> 3;          // group (b-pair) 0..31
    const int q    = bid & 7;           // sibling / XCD / j-eighth / s-sixteenth
    const int gq   = g*8 + q;
    const int b0c  = g*2;
    const int j0   = q*64;
    const int s0   = q*16;

    // ---- init: enc own rows fp32 -> LDS fp16 (read once from HBM/L3) ----
    {
        const float2* e2 = (const float2*)encf;
#pragma unroll
        for (int r = 0; r < 8; ++r) {
            const int u = tid + 1024*r;             // 8192 u32 chunks
            const int bb = u >> 12, rest = u & 4095;
            const int i = rest >> 8, p = rest & 255;
            const float2 v = e2[(size_t)((s0+i)*Bn + b0c+bb)*256 + p];
            ((u32*)enc_lds[bb][i])[p] = pack2h(v.x, v.y);
        }
    }
    { const int bb = tid >> 9, jx = tid & 511; h_s[bb][jx] = 0.0f; hh_s[bb][jx] = 0; }
    // loop-invariant vat weights in registers (this lane's 16 elems: [8*l5..) and [256+8*l5..))
    const float4 WV0 = ((const float4*)wvat)[2*l5];
    const float4 WV1 = ((const float4*)wvat)[2*l5+1];
    const float4 WV2 = ((const float4*)wvat)[64+2*l5];
    const float4 WV3 = ((const float4*)wvat)[64+2*l5+1];
    const float bv = bvat[0];
    __syncthreads();

    for (int t = 0; t < TSn; ++t) {
        const u32 tgtc = 8u*(t+1);

        // ---- A: own scores. wave = s-row (wid), halves = b. 32-lane dot, 5-level reduce.
        {
            const uint4 E0 = ((const uint4*)enc_lds[half][wid])[l5];
            const uint4 E1 = ((const uint4*)enc_lds[half][wid])[32+l5];
            const float4 H0 = ((const float4*)h_s[half])[2*l5];
            const float4 H1 = ((const float4*)h_s[half])[2*l5+1];
            const float4 H2 = ((const float4*)h_s[half])[64+2*l5];
            const float4 H3 = ((const float4*)h_s[half])[64+2*l5+1];
            float2 e; float acc;
            e = h2f(E0.x); acc  = fast_tanh(e.x+H0.x)*WV0.x + fast_tanh(e.y+H0.y)*WV0.y;
            e = h2f(E0.y); acc += fast_tanh(e.x+H0.z)*WV0.z + fast_tanh(e.y+H0.w)*WV0.w;
            e = h2f(E0.z); acc += fast_tanh(e.x+H1.x)*WV1.x + fast_tanh(e.y+H1.y)*WV1.y;
            e = h2f(E0.w); acc += fast_tanh(e.x+H1.z)*WV1.z + fast_tanh(e.y+H1.w)*WV1.w;
            e = h2f(E1.x); acc += fast_tanh(e.x+H2.x)*WV2.x + fast_tanh(e.y+H2.y)*WV2.y;
            e = h2f(E1.y); acc += fast_tanh(e.x+H2.z)*WV2.z + fast_tanh(e.y+H2.w)*WV2.w;
            e = h2f(E1.z); acc += fast_tanh(e.x+H3.x)*WV3.x + fast_tanh(e.y+H3.y)*WV3.y;
            e = h2f(E1.w); acc += fast_tanh(e.x+H3.z)*WV3.z + fast_tanh(e.y+H3.w)*WV3.w;
            acc = half_sum(acc);
            if (l5 == 0) sc_s[half][wid] = acc + bv;
        }
        __syncthreads();

        // ---- B: local max/sum of own 16 scores (flash-style), publish (m,l)
        if (wid < 2) {
            const int bb = wid;
            const float sc = (lane < 16) ? sc_s[bb][lane] : -3.0e38f;
            const float m = wave_max(sc);
            const float ev = (lane < 16) ? __expf(sc - m) : 0.0f;
            const float l = wave_sum(ev);
            if (lane < 16) attnw_s[bb][lane] = ev;
            if (lane == 0) { ML[gq*4 + bb*2] = m; ML[gq*4 + bb*2 + 1] = l; }
        }
        __syncthreads();

        // ---- C: partial ctx over own 16 s, publish fp16
        {
            const int bb = tid >> 9, rest = tid & 511;
            const int p = rest & 255, c = rest >> 8;
            float ax = 0.0f, ay = 0.0f;
#pragma unroll
            for (int i2 = 0; i2 < 8; ++i2) {
                const int s = c*8 + i2;
                const float a = attnw_s[bb][s];
                const float2 ef = h2f(((const u32*)enc_lds[bb][s])[p]);
                ax += a*ef.x; ay += a*ef.y;
            }
            pctx_s[bb][c][p] = make_float2(ax, ay);
        }
        __syncthreads();
        if (tid < 512) {
            const int bb = tid >> 8, p = tid & 255;
            const float2 u0 = pctx_s[bb][0][p], u1 = pctx_s[bb][1][p];
            PCTX[(gq*2+bb)*256 + p] = pack2h(u0.x+u1.x, u0.y+u1.y);
        }
        sib_arrive(CNT + g);

        // ---- D (in exchange shadow): h-side GRU dots for own j-slice
        float gh_r[4], gh_z[4], gh_n[4];
        {
            const uint4 HH0 = ((const uint4*)hh_s[half])[l5];
            const uint4 HH1 = ((const uint4*)hh_s[half])[32+l5];
#pragma unroll
            for (int k = 0; k < 4; ++k) {
                const int j = j0 + wid*4 + k;
                const uint4 R0 = ((const uint4*)(Whh_h + (size_t)j*Hn))[l5];
                const uint4 R1 = ((const uint4*)(Whh_h + (size_t)j*Hn))[32+l5];
                const uint4 Z0 = ((const uint4*)(Whh_h + (size_t)(Hn+j)*Hn))[l5];
                const uint4 Z1 = ((const uint4*)(Whh_h + (size_t)(Hn+j)*Hn))[32+l5];
                const uint4 N0 = ((const uint4*)(Whh_h + (size_t)(2*Hn+j)*Hn))[l5];
                const uint4 N1 = ((const uint4*)(Whh_h + (size_t)(2*Hn+j)*Hn))[32+l5];
                float ar = dot8h(R1, HH1, dot8h(R0, HH0, 0.0f));
                float az = dot8h(Z1, HH1, dot8h(Z0, HH0, 0.0f));
                float an = dot8h(N1, HH1, dot8h(N0, HH0, 0.0f));
                gh_r[k] = half_sum(ar);
                gh_z[k] = half_sum(az);
                gh_n[k] = half_sum(an);
            }
        }
        sib_wait(CNT + g, tgtc);

        // ---- E: flash-combine ctx + embedding -> ec_s
        if (wid < 2) {
            const int bb = wid;
            float vm = -3.0e38f, vl = 0.0f;
            if (lane < 8) {
                vm = ML[((g*8+lane)*2 + bb)*2];
                vl = ML[((g*8+lane)*2 + bb)*2 + 1];
            }
            const float M = wave_max(vm);
            const float f = (lane < 8) ? __expf(vm - M) : 0.0f;
            const float L = wave_sum(f*vl);
            if (lane < 8) fac_s[bb][lane] = f;
            if (lane == 0) linv_s[bb] = 1.0f / L;
        }
        __syncthreads();
        if (tid < 512) {
            const int bb = tid >> 8, p = tid & 255;
            u32 pc[8];
#pragma unroll
            for (int qq = 0; qq < 8; ++qq) pc[qq] = PCTX[((g*8+qq)*2+bb)*256 + p];
            float ax = 0.0f, ay = 0.0f;
#pragma unroll
            for (int qq = 0; qq < 8; ++qq) {
                const float f = fac_s[bb][qq];
                const float2 v = h2f(pc[qq]);
                ax += f*v.x; ay += f*v.y;
            }
            const float inv = linv_s[bb];
            ((u32*)ec_s[bb])[256 + p] = pack2h(ax*inv, ay*inv);
        } else {
            const int i2 = tid - 512, bb = i2 >> 8, p = i2 & 255;
            const int sym = tgt[t*Bn + b0c + bb];
            ((u32*)ec_s[bb])[p] = ((const u32*)(Wemb_h + (size_t)sym*Hn))[p];
        }
        __syncthreads();

        // ---- F: x for own j-slice (1024-elem dot, halves = b), publish
#pragma unroll
        for (int k = 0; k < 4; ++k) {
            const int j = j0 + wid*4 + k;
            const u16* row = Wcomb_h + (size_t)j*2*Hn;
            const uint4 W0 = ((const uint4*)row)[l5];
            const uint4 W1 = ((const uint4*)row)[32+l5];
            const uint4 W2 = ((const uint4*)row)[64+l5];
            const uint4 W3 = ((const uint4*)row)[96+l5];
            const uint4 C0 = ((const uint4*)ec_s[half])[l5];
            const uint4 C1 = ((const uint4*)ec_s[half])[32+l5];
            const uint4 C2 = ((const uint4*)ec_s[half])[64+l5];
            const uint4 C3 = ((const uint4*)ec_s[half])[96+l5];
            float acc = dot8h(W3, C3, dot8h(W2, C2, dot8h(W1, C1, dot8h(W0, C0, 0.0f))));
            acc = half_sum(acc);
            if (l5 == 0) xst[half][wid*4+k] = f2h(fmaxf(acc + bcomb[j], 0.0f));
        }
        __syncthreads();
        if (tid < 64) {
            const int bb = tid >> 5, l = tid & 31;
            XEX[(gq*2+bb)*32 + l] = (u32)xst[bb][2*l] | ((u32)xst[bb][2*l+1] << 16);
        }
        sib_arrive(CNT + 32 + g);
        sib_wait(CNT + 32 + g, tgtc);
        if (tid < 512) {
            const int qq = tid >> 6, bb = (tid >> 5) & 1, l = tid & 31;
            ((u32*)x_s[bb])[qq*32 + l] = XEX[((g*8+qq)*2+bb)*32 + l];
        }
        __syncthreads();

        // ---- H: x-side dots + gate combine -> h_new own slice, publish
        {
            const uint4 X0 = ((const uint4*)x_s[half])[l5];
            const uint4 X1 = ((const uint4*)x_s[half])[32+l5];
#pragma unroll
            for (int k = 0; k < 4; ++k) {
                const int j = j0 + wid*4 + k;
                const uint4 R0 = ((const uint4*)(Wih_h + (size_t)j*Hn))[l5];
                const uint4 R1 = ((const uint4*)(Wih_h + (size_t)j*Hn))[32+l5];
                const uint4 Z0 = ((const uint4*)(Wih_h + (size_t)(Hn+j)*Hn))[l5];
                const uint4 Z1 = ((const uint4*)(Wih_h + (size_t)(Hn+j)*Hn))[32+l5];
                const uint4 N0 = ((const uint4*)(Wih_h + (size_t)(2*Hn+j)*Hn))[l5];
                const uint4 N1 = ((const uint4*)(Wih_h + (size_t)(2*Hn+j)*Hn))[32+l5];
                float ar = dot8h(R1, X1, dot8h(R0, X0, 0.0f));
                float az = dot8h(Z1, X1, dot8h(Z0, X0, 0.0f));
                float an = dot8h(N1, X1, dot8h(N0, X0, 0.0f));
                ar = half_sum(ar); az = half_sum(az); an = half_sum(an);
                if (l5 == 0) {
                    const float r = fast_sigmoid(ar + gh_r[k] + bih[j] + bhh[j]);
                    const float z = fast_sigmoid(az + gh_z[k] + bih[Hn+j] + bhh[Hn+j]);
                    const float n = fast_tanh(an + bih[2*Hn+j] + r*(gh_n[k] + bhh[2*Hn+j]));
                    const float hv = (1.0f - z)*n + z*h_s[half][j];
                    hn16_s[half][wid*4+k] = f2h(hv);
                    HEX[(gq*2+half)*64 + wid*4 + k] = hv;
                }
            }
        }
        __syncthreads();

        // ---- I: partial logits over own j-slice (half-wave per (b,v) task)
#pragma unroll
        for (int m = 0; m < 7; ++m) {
            const int id = m*32 + wid*2 + half;
            if (id < 200) {
                const int bb = id & 1, v = id >> 1;
                const u32 wv = ((const u32*)(Wout_h + (size_t)v*Hn))[q*32 + l5];
                const u32 hv = ((const u32*)hn16_s[bb])[l5];
                float acc = dot2acc(wv, hv, 0.0f);
                acc = half_sum(acc);
                if (l5 == 0) plog_s[bb][v] = acc;
            }
        }
        __syncthreads();
        if (tid < 200) {
            const int bb = tid >= 100 ? 1 : 0, v = tid - bb*100;
            PLOG[(gq*2+bb)*100 + v] = plog_s[bb][v];
        }
        sib_arrive(CNT + 64 + g);
        sib_wait(CNT + 64 + g, tgtc);

        // ---- J: consume h_new (all threads); final logits (sibling 0->b0, 1->b1)
        {
            const int qq = tid >> 7, bb = (tid >> 6) & 1, jj = tid & 63;
            const float hv = HEX[((g*8+qq)*2+bb)*64 + jj];
            h_s[bb][qq*64 + jj] = hv;
            hh_s[bb][qq*64 + jj] = f2h(hv);
        }
        if (q < 2 && wid == 0) {
            const int bb = q;
            float pv0[8], pv1[8];
#pragma unroll
            for (int qq = 0; qq < 8; ++qq) {
                pv0[qq] = PLOG[((g*8+qq)*2+bb)*100 + lane];
                pv1[qq] = (lane < 36) ? PLOG[((g*8+qq)*2+bb)*100 + 64 + lane] : 0.0f;
            }
            float a0 = bout[lane];
            float a1 = (lane < 36) ? bout[64+lane] : 0.0f;
#pragma unroll
            for (int qq = 0; qq < 8; ++qq) { a0 += pv0[qq]; a1 += pv1[qq]; }
            const float l0 = a0;
            const float l1 = (lane < 36) ? a1 : -3.0e38f;
            const float mx = wave_max(fmaxf(l0, l1));
            const float e0 = __expf(l0 - mx);
            const float e1 = (lane < 36) ? __expf(l1 - mx) : 0.0f;
            const float lse = mx + __logf(wave_sum(e0 + e1));
            float* op = out + ((size_t)(b0c+bb)*TSn + t)*Vn;
            op[lane] = l0 - lse;
            if (lane < 36) op[64+lane] = l1 - lse;
        }
        __syncthreads();
    }
}

extern "C" void kernel_launch(void* const* d_in, const int* in_sizes, int n_in,
                              void* d_out, int out_size, void* d_ws, size_t ws_size,
                              hipStream_t stream) {
    const float* enc   = (const float*)d_in[0];
    const float* Wemb  = (const float*)d_in[1];
    const float* Wcomb = (const float*)d_in[2];
    const float* bcomb = (const float*)d_in[3];
    const float* Wih   = (const float*)d_in[4];
    const float* Whh   = (const float*)d_in[5];
    const float* bih   = (const float*)d_in[6];
    const float* bhh   = (const float*)d_in[7];
    const float* Wout  = (const float*)d_in[8];
    const float* bout  = (const float*)d_in[9];
    const float* wvat  = (const float*)d_in[10];
    const float* bvat  = (const float*)d_in[11];
    const int*   tgt   = (const int*)d_in[12];
    float* out = (float*)d_out;
    char*  ws  = (char*)d_ws;

    conv_f16<<<256, 256, 0, stream>>>(Wemb, Wcomb, Wih, Whh, Wout, ws);

    void* args[] = { &enc, &bcomb, &bih, &bhh, &bout, &wvat, &bvat, &tgt, &out, &ws };
    hipLaunchCooperativeKernel((const void*)bahdanau_decoder,
                               dim3(256), dim3(1024), args, 0, stream);
}